// Round 4
// baseline (259.509 us; speedup 1.0000x reference)
//
#include <hip/hip_runtime.h>

// Problem constants
#define B 8
#define S 4096
#define H 32
#define D 128
#define DM 4096   // H*D

#define CS 32             // s-rows per chunk
#define NCHUNK (S / CS)   // 128 chunks -> 1024 blocks (4 per CU)
#define NT 1024
#define PSTR 132          // partial record stride (floats): 128 O + m + l (+pad)

// ---------------------------------------------------------------------------
// Kernel 1: q = hidden @ Wq^T + bq  (round-1 proven version: 2 cols/wave).
// Wq rows read exactly once, coalesced float4; hidden L2-resident and its
// loads amortized over 2 output columns.
// ---------------------------------------------------------------------------
__global__ __launch_bounds__(256) void qproj_kernel(
    const float* __restrict__ hidden, const float* __restrict__ Wq,
    const float* __restrict__ bq, float* __restrict__ qout)
{
    const int lane = threadIdx.x & 63;
    const int wave = threadIdx.x >> 6;
    const int j0 = (blockIdx.x * 4 + wave) * 2;
    const int j1 = j0 + 1;

    const float4* __restrict__ w0 = (const float4*)(Wq + (size_t)j0 * DM);
    const float4* __restrict__ w1 = (const float4*)(Wq + (size_t)j1 * DM);
    const float4* __restrict__ hid = (const float4*)hidden;

    float a0[B], a1[B];
#pragma unroll
    for (int b = 0; b < B; ++b) { a0[b] = 0.f; a1[b] = 0.f; }

#pragma unroll 4
    for (int i = 0; i < DM / (4 * 64); ++i) {   // 16 iterations
        const int idx = lane + 64 * i;
        const float4 wv0 = w0[idx];
        const float4 wv1 = w1[idx];
#pragma unroll
        for (int b = 0; b < B; ++b) {
            const float4 hv = hid[b * (DM / 4) + idx];
            a0[b] += wv0.x * hv.x + wv0.y * hv.y + wv0.z * hv.z + wv0.w * hv.w;
            a1[b] += wv1.x * hv.x + wv1.y * hv.y + wv1.z * hv.z + wv1.w * hv.w;
        }
    }
#pragma unroll
    for (int b = 0; b < B; ++b) {
#pragma unroll
        for (int mk = 1; mk <= 32; mk <<= 1) {
            a0[b] += __shfl_xor(a0[b], mk);
            a1[b] += __shfl_xor(a1[b], mk);
        }
    }
    if (lane == 0) {
        const float bias0 = bq[j0];
        const float bias1 = bq[j1];
#pragma unroll
        for (int b = 0; b < B; ++b) {
            qout[b * DM + j0] = a0[b] + bias0;
            qout[b * DM + j1] = a1[b] + bias1;
        }
    }
}

// ---------------------------------------------------------------------------
// Kernel 2: flash-decode partial, linear-stream layout (clean retest).
// One block per (b, 32-row s-chunk), ALL 32 heads. Thread tid owns elements
// [4*tid, 4*tid+4) of every 16 KB row -> block reads K then V as a single
// linear 512 KB stream each. Gang g = tid>>5 is head g. No __syncthreads
// (gang-local data; LDS RAW within a wave is ordered).
// ---------------------------------------------------------------------------
__global__ __launch_bounds__(NT) void attn_partial(
    const float* __restrict__ kptr, const float* __restrict__ vptr,
    const float* __restrict__ qws, float* __restrict__ part)
{
    __shared__ float sc[H][CS + 1];     // 4.1 KB

    const int tid = threadIdx.x;
    const int g   = tid >> 5;           // head 0..31
    const int l   = tid & 31;
    const int c   = blockIdx.x & (NCHUNK - 1);
    const int b   = blockIdx.x >> 7;    // NCHUNK = 128

    const size_t base = ((size_t)b * S + (size_t)c * CS) * DM;
    const float4* __restrict__ kb = (const float4*)(kptr + base);
    const float4* __restrict__ vb = (const float4*)(vptr + base);

    const float4 q4 = *(const float4*)(qws + (size_t)b * DM + 4 * tid);

    // ---- Phase 1: scores (one 16 KB row per iteration, fully coalesced) ----
#pragma unroll 8
    for (int s = 0; s < CS; ++s) {
        const float4 k4 = kb[(size_t)s * (DM / 4) + tid];
        float p = q4.x * k4.x + q4.y * k4.y + q4.z * k4.z + q4.w * k4.w;
        p += __shfl_xor(p, 1);
        p += __shfl_xor(p, 2);
        p += __shfl_xor(p, 4);
        p += __shfl_xor(p, 8);
        p += __shfl_xor(p, 16);
        if (l == 0) sc[g][s] = p;
    }

    // ---- gang-local softmax over the chunk (32 scores per head) ----
    const float sv = sc[g][l];
    float m = sv;
#pragma unroll
    for (int mk = 1; mk <= 16; mk <<= 1) m = fmaxf(m, __shfl_xor(m, mk));
    const float e = __expf(sv - m);
    float sum = e;
#pragma unroll
    for (int mk = 1; mk <= 16; mk <<= 1) sum += __shfl_xor(sum, mk);
    sc[g][l] = e;

    // ---- Phase 2: partial O = exp(S) @ V (linear V stream) ----
    float4 acc = make_float4(0.f, 0.f, 0.f, 0.f);
#pragma unroll 8
    for (int s = 0; s < CS; ++s) {
        const float p = sc[g][s];       // broadcast within gang
        const float4 v4 = vb[(size_t)s * (DM / 4) + tid];
        acc.x += p * v4.x;
        acc.y += p * v4.y;
        acc.z += p * v4.z;
        acc.w += p * v4.w;
    }

    // ---- write partial record for (b, head g, chunk c) ----
    float* rec = part + ((size_t)(b * H + g) * NCHUNK + c) * PSTR;
    *(float4*)(rec + 4 * l) = acc;
    if (l == 0) { rec[D] = m; rec[D + 1] = sum; }
}

// ---------------------------------------------------------------------------
// Kernel 3: merge the NCHUNK partials per (b,h).
// ---------------------------------------------------------------------------
__global__ __launch_bounds__(128) void combine_kernel(
    const float* __restrict__ part, float* __restrict__ out)
{
    const int bh = blockIdx.x;          // 0..255
    const int d  = threadIdx.x;         // 0..127
    const float* rec = part + (size_t)bh * NCHUNK * PSTR;

    float M = -3.4e38f;
#pragma unroll 8
    for (int c = 0; c < NCHUNK; ++c) M = fmaxf(M, rec[c * PSTR + D]);
    float denom = 0.f, o = 0.f;
#pragma unroll 8
    for (int c = 0; c < NCHUNK; ++c) {
        const float w = __expf(rec[c * PSTR + D] - M);
        denom += w * rec[c * PSTR + D + 1];
        o     += w * rec[c * PSTR + d];
    }
    out[(size_t)bh * D + d] = o / denom;
}

extern "C" void kernel_launch(void* const* d_in, const int* in_sizes, int n_in,
                              void* d_out, int out_size, void* d_ws, size_t ws_size,
                              hipStream_t stream)
{
    const float* hidden = (const float*)d_in[0];
    const float* keys   = (const float*)d_in[1];
    const float* vals   = (const float*)d_in[2];
    const float* Wq     = (const float*)d_in[3];
    const float* bq     = (const float*)d_in[4];
    float* outp = (float*)d_out;
    float* qws  = (float*)d_ws;                   // B*DM floats = 128 KB
    float* part = qws + (size_t)B * DM;           // 256*128*132 floats ≈ 17.3 MB

    qproj_kernel<<<DM / 8, 256, 0, stream>>>(hidden, Wq, bq, qws);
    attn_partial<<<B * NCHUNK, NT, 0, stream>>>(keys, vals, qws, part);
    combine_kernel<<<B * H, 128, 0, stream>>>(part, outp);
}

// Round 5
// 217.792 us; speedup vs baseline: 1.1915x; 1.1915x over previous
//
#include <hip/hip_runtime.h>

// Problem constants
#define B 8
#define S 4096
#define H 32
#define D 128
#define DM 4096   // H*D

#define NT 1024
#define WAVES 16  // NT/64

typedef float v4f __attribute__((ext_vector_type(4)));

// ---------------------------------------------------------------------------
// Kernel 1: q = hidden @ Wq^T + bq  (round-1 structure; Wq via non-temporal
// streaming loads — read exactly once, no reuse).
// ---------------------------------------------------------------------------
__global__ __launch_bounds__(256) void qproj_kernel(
    const float* __restrict__ hidden, const float* __restrict__ Wq,
    const float* __restrict__ bq, float* __restrict__ qout)
{
    const int lane = threadIdx.x & 63;
    const int wave = threadIdx.x >> 6;
    const int j0 = (blockIdx.x * 4 + wave) * 2;
    const int j1 = j0 + 1;

    const v4f* __restrict__ w0 = (const v4f*)(Wq + (size_t)j0 * DM);
    const v4f* __restrict__ w1 = (const v4f*)(Wq + (size_t)j1 * DM);
    const v4f* __restrict__ hid = (const v4f*)hidden;

    float a0[B], a1[B];
#pragma unroll
    for (int b = 0; b < B; ++b) { a0[b] = 0.f; a1[b] = 0.f; }

#pragma unroll 4
    for (int i = 0; i < DM / (4 * 64); ++i) {   // 16 iterations
        const int idx = lane + 64 * i;
        const v4f wv0 = __builtin_nontemporal_load(w0 + idx);
        const v4f wv1 = __builtin_nontemporal_load(w1 + idx);
#pragma unroll
        for (int b = 0; b < B; ++b) {
            const v4f hv = hid[b * (DM / 4) + idx];
            a0[b] += wv0[0] * hv[0] + wv0[1] * hv[1] + wv0[2] * hv[2] + wv0[3] * hv[3];
            a1[b] += wv1[0] * hv[0] + wv1[1] * hv[1] + wv1[2] * hv[2] + wv1[3] * hv[3];
        }
    }
#pragma unroll
    for (int b = 0; b < B; ++b) {
#pragma unroll
        for (int mk = 1; mk <= 32; mk <<= 1) {
            a0[b] += __shfl_xor(a0[b], mk);
            a1[b] += __shfl_xor(a1[b], mk);
        }
    }
    if (lane == 0) {
        const float bias0 = bq[j0];
        const float bias1 = bq[j1];
#pragma unroll
        for (int b = 0; b < B; ++b) {
            qout[b * DM + j0] = a0[b] + bias0;
            qout[b * DM + j1] = a1[b] + bias1;
        }
    }
}

// ---------------------------------------------------------------------------
// Kernel 2: attention decode — EXACT round-1 structure (fastest measured),
// with K/V loads switched to non-temporal streaming loads (data is read
// exactly once; avoid L1/L2/L3 allocation churn).
// ---------------------------------------------------------------------------
__global__ __launch_bounds__(NT) void attn_kernel(
    const float* __restrict__ kptr, const float* __restrict__ vptr,
    const float* __restrict__ qws, float* __restrict__ out)
{
    __shared__ float sc[S];             // 16 KB
    __shared__ float red[WAVES];
    __shared__ float outp[WAVES][D];    // 8 KB

    const int tid  = threadIdx.x;
    const int lane = tid & 63;
    const int wave = tid >> 6;
    const int g    = lane >> 5;         // 32-lane group: 0/1
    const int l    = lane & 31;
    const int b    = blockIdx.x >> 5;   // H = 32
    const int h    = blockIdx.x & (H - 1);

    const size_t base = ((size_t)b * S * H + h) * D;  // (b, s=0, h, d=0)
    const float* kb = kptr + base;
    const float* vb = vptr + base;

    const v4f q4 = *(const v4f*)(qws + (size_t)b * DM + h * D + 4 * l);

    // ---- Phase 1: scores ----
#pragma unroll 2
    for (int it = 0; it < S / 32; ++it) {           // 128 iterations
        const int s = it * 32 + 2 * wave + g;
        const v4f k4 = __builtin_nontemporal_load(
            (const v4f*)(kb + (size_t)s * DM + 4 * l));
        float p = q4[0] * k4[0] + q4[1] * k4[1] + q4[2] * k4[2] + q4[3] * k4[3];
        p += __shfl_xor(p, 16);
        p += __shfl_xor(p, 8);
        p += __shfl_xor(p, 4);
        p += __shfl_xor(p, 2);
        p += __shfl_xor(p, 1);
        if (l == 0) sc[s] = p;
    }
    __syncthreads();

    // ---- Softmax: block max ----
    float m = -3.4e38f;
    for (int i = tid; i < S; i += NT) m = fmaxf(m, sc[i]);
#pragma unroll
    for (int mk = 1; mk <= 32; mk <<= 1) m = fmaxf(m, __shfl_xor(m, mk));
    if (lane == 0) red[wave] = m;
    __syncthreads();
    float M = red[0];
#pragma unroll
    for (int w = 1; w < WAVES; ++w) M = fmaxf(M, red[w]);

    // ---- exp + block sum (unnormalized exp kept in sc) ----
    float lsum = 0.f;
    for (int i = tid; i < S; i += NT) {
        const float e = __expf(sc[i] - M);
        sc[i] = e;
        lsum += e;
    }
#pragma unroll
    for (int mk = 1; mk <= 32; mk <<= 1) lsum += __shfl_xor(lsum, mk);
    __syncthreads();
    if (lane == 0) red[wave] = lsum;
    __syncthreads();
    float tot = 0.f;
#pragma unroll
    for (int w = 0; w < WAVES; ++w) tot += red[w];
    const float inv = 1.0f / tot;

    // ---- Phase 2: out = P @ V ----
    v4f acc = {0.f, 0.f, 0.f, 0.f};
    const int s0 = wave * (S / WAVES);  // 256 contiguous s per wave
#pragma unroll 2
    for (int i = 0; i < S / WAVES; i += 2) {
        const int s = s0 + i + g;
        const float p = sc[s];          // LDS broadcast within each 32-group
        const v4f v4 = __builtin_nontemporal_load(
            (const v4f*)(vb + (size_t)s * DM + 4 * l));
        acc[0] += p * v4[0];
        acc[1] += p * v4[1];
        acc[2] += p * v4[2];
        acc[3] += p * v4[3];
    }
    acc[0] += __shfl_xor(acc[0], 32);
    acc[1] += __shfl_xor(acc[1], 32);
    acc[2] += __shfl_xor(acc[2], 32);
    acc[3] += __shfl_xor(acc[3], 32);
    if (g == 0) *(v4f*)(&outp[wave][4 * l]) = acc;
    __syncthreads();

    // ---- final cross-wave reduce + write ----
    if (tid < D) {
        float r = 0.f;
#pragma unroll
        for (int w = 0; w < WAVES; ++w) r += outp[w][tid];
        out[(size_t)(b * H + h) * D + tid] = r * inv;
    }
}

extern "C" void kernel_launch(void* const* d_in, const int* in_sizes, int n_in,
                              void* d_out, int out_size, void* d_ws, size_t ws_size,
                              hipStream_t stream)
{
    const float* hidden = (const float*)d_in[0];
    const float* keys   = (const float*)d_in[1];
    const float* vals   = (const float*)d_in[2];
    const float* Wq     = (const float*)d_in[3];
    const float* bq     = (const float*)d_in[4];
    float* outp = (float*)d_out;
    float* qws  = (float*)d_ws;   // B*DM floats = 128 KB scratch for q

    qproj_kernel<<<DM / 8, 256, 0, stream>>>(hidden, Wq, bq, qws);
    attn_kernel<<<B * H, NT, 0, stream>>>(keys, vals, qws, outp);
}